// Round 2
// baseline (54632.233 us; speedup 1.0000x reference)
//
#include <hip/hip_runtime.h>
#include <cstdint>
#include <cstddef>

#define DEVFN __device__ __forceinline__

static constexpr int B  = 32;
static constexpr int T1 = 1024;
static constexpr int F0 = 240;
static constexpr int H  = 512;
static constexpr int G3 = 3 * H;   // 1536

// ---- module-scope scratch (device .bss, ~537 MB; avoids unknown ws_size) ----
__device__ float g_XPF[(size_t)B * T1 * G3];
__device__ float g_XPB[(size_t)B * T1 * G3];
__device__ float g_YF [(size_t)B * T1 * H];
__device__ float g_YB [(size_t)B * T1 * H];
__device__ float g_HFIN[2 * B * H];
__device__ int   g_MK1[B * T1];
__device__ int   g_MK2[B * (T1 / 2)];
__device__ int   g_MK3[B * (T1 / 4)];
__device__ int   g_MK4[B * (T1 / 8)];

DEVFN float fsig(float x)  { return 1.0f / (1.0f + expf(-x)); }

// ---------------------------------------------------------------------------
// mask for layer 1: one wave per (b,t) row; any nonzero among 240 feats
// ---------------------------------------------------------------------------
__global__ __launch_bounds__(256) void mask1_kernel(const float* __restrict__ x,
                                                    int* __restrict__ mask) {
    int wave = blockIdx.x * 4 + (threadIdx.x >> 6);
    int lane = threadIdx.x & 63;
    if (wave >= B * T1) return;
    const float* row = x + (size_t)wave * F0;
    int nz = 0;
    for (int f = lane; f < F0; f += 64) nz |= (row[f] != 0.0f);
    nz = __any(nz);
    if (lane == 0) mask[wave] = nz ? 1 : 0;
}

// mask_{l+1}[b][t] = mask_l[b][2t] | mask_l[b][2t+1]
__global__ __launch_bounds__(256) void mask_down(const int* __restrict__ mp,
                                                 int* __restrict__ m, int n, int Tn) {
    int i = blockIdx.x * 256 + threadIdx.x;
    if (i >= n) return;
    int b = i / Tn, t = i - b * Tn;
    m[i] = mp[b * 2 * Tn + 2 * t] | mp[b * 2 * Tn + 2 * t + 1];
}

// ---------------------------------------------------------------------------
// xproj GEMM: C[M][1536] = A[M][K] @ W[K][1536]   (bias folded into recurrence)
// PYR=0: A is a plain row-major [M][K] buffer.
// PYR=1: A row m=(b*Tn+t), col f in [0,2048) gathers the pyramid concat of the
//        previous layer's (already mask-zeroed) outputs YFp/YBp, Tprev=2*Tn.
// Tile 128x128, BK=16, 256 threads, 8x8 microtile.
// ---------------------------------------------------------------------------
template <int PYR>
__global__ __launch_bounds__(256)
void gemm_xproj(const float* __restrict__ A,
                const float* __restrict__ YFp, const float* __restrict__ YBp,
                const float* __restrict__ W, float* __restrict__ C,
                int M, int K, int Tn) {
    __shared__ float At[16][128];
    __shared__ float Bs[16][128];
    int tid = threadIdx.x;
    int n0 = blockIdx.x * 128;
    int m0 = blockIdx.y * 128;
    int tm = tid & 15, tn = tid >> 4;
    float acc[8][8] = {};

    for (int k0 = 0; k0 < K; k0 += 16) {
        // stage A (transposed into LDS)
#pragma unroll
        for (int it = 0; it < 2; ++it) {
            int i = tid + it * 256;          // 0..511
            int m = i >> 2, kg = (i & 3) * 4;
            int gm = m0 + m, gk = k0 + kg;
            float4 v;
            if (PYR == 0) {
                v = *(const float4*)(A + (size_t)gm * K + gk);
            } else {
                int b = gm / Tn, t = gm - b * Tn;
                int s = 2 * t + (gk >> 10);
                int g = gk & 1023;
                const float* src = (g < 512)
                    ? (YFp + ((size_t)(b * 2 * Tn + s) * 512 + g))
                    : (YBp + ((size_t)(b * 2 * Tn + s) * 512 + (g - 512)));
                v = *(const float4*)src;
            }
            At[kg + 0][m] = v.x; At[kg + 1][m] = v.y;
            At[kg + 2][m] = v.z; At[kg + 3][m] = v.w;
        }
        // stage B
#pragma unroll
        for (int it = 0; it < 2; ++it) {
            int i = tid + it * 256;          // 0..511
            int kk = i >> 5, n4 = (i & 31) * 4;
            *(float4*)&Bs[kk][n4] =
                *(const float4*)(W + (size_t)(k0 + kk) * G3 + n0 + n4);
        }
        __syncthreads();
#pragma unroll
        for (int kk = 0; kk < 16; ++kk) {
            float a[8], bb[8];
            *(float4*)&a[0]  = *(float4*)&At[kk][tm * 8];
            *(float4*)&a[4]  = *(float4*)&At[kk][tm * 8 + 4];
            *(float4*)&bb[0] = *(float4*)&Bs[kk][tn * 8];
            *(float4*)&bb[4] = *(float4*)&Bs[kk][tn * 8 + 4];
#pragma unroll
            for (int i = 0; i < 8; ++i)
#pragma unroll
                for (int j = 0; j < 8; ++j) acc[i][j] += a[i] * bb[j];
        }
        __syncthreads();
    }
#pragma unroll
    for (int i = 0; i < 8; ++i) {
        size_t row = (size_t)(m0 + tm * 8 + i) * G3 + n0 + tn * 8;
        *(float4*)(C + row)     = *(float4*)&acc[i][0];
        *(float4*)(C + row + 4) = *(float4*)&acc[i][4];
    }
}

// ---------------------------------------------------------------------------
// GRU recurrence: one WG per (batch, dir). 384 threads; thread owns 4 columns
// of the 1536-wide inner product. h lives in LDS; rk streamed from L2.
// dir = blockIdx&1 so (with round-robin XCD dispatch) each XCD caches mostly
// one direction's 3MB weight matrix.
// ---------------------------------------------------------------------------
__global__ __launch_bounds__(384)
void gru_rec(const float* __restrict__ xpF, const float* __restrict__ xpB,
             const float* __restrict__ rkF, const float* __restrict__ rkB,
             const float* __restrict__ bF,  const float* __restrict__ bB,
             float* __restrict__ ysF, float* __restrict__ ysB,
             float* __restrict__ hfin,                 // [2][B][H]
             const int* __restrict__ mask, int T) {
    int dir = blockIdx.x & 1;
    int b   = blockIdx.x >> 1;
    const float* xp = dir ? xpB : xpF;
    const float* rk = dir ? rkB : rkF;
    const float* bw = dir ? bB  : bF;
    float*       ys = dir ? ysB : ysF;

    __shared__ float h[H];
    __shared__ float inner[G3];
    __shared__ float zc[H], rc[H], bh0[H], bh1[H];

    int tid = threadIdx.x;
    for (int u = tid; u < H; u += 384) {
        h[u]   = 0.0f;
        zc[u]  = bw[u]         + bw[G3 + u];           // b0_z + b1_z
        rc[u]  = bw[H + u]     + bw[G3 + H + u];       // b0_r + b1_r
        bh0[u] = bw[2 * H + u];                        // b0_h (outside r)
        bh1[u] = bw[G3 + 2 * H + u];                   // b1_h (inside r*(...))
    }
    __syncthreads();

    const float* wp   = rk + tid * 4;   // this thread's 4 columns
    const int*   mrow = mask + b * T;

    for (int step = 0; step < T; ++step) {
        int tt = dir ? (T - 1 - step) : step;
        if (mrow[tt]) {
            float a0 = 0.f, a1 = 0.f, a2 = 0.f, a3 = 0.f;
#pragma unroll 4
            for (int k4 = 0; k4 < H / 4; ++k4) {
                float4 hv = *(const float4*)&h[k4 << 2];
                const float* wr = wp + (size_t)(k4 << 2) * G3;
                float4 w0 = *(const float4*)(wr);
                float4 w1 = *(const float4*)(wr + G3);
                float4 w2 = *(const float4*)(wr + 2 * G3);
                float4 w3 = *(const float4*)(wr + 3 * G3);
                a0 += hv.x * w0.x + hv.y * w1.x + hv.z * w2.x + hv.w * w3.x;
                a1 += hv.x * w0.y + hv.y * w1.y + hv.z * w2.y + hv.w * w3.y;
                a2 += hv.x * w0.z + hv.y * w1.z + hv.z * w2.z + hv.w * w3.z;
                a3 += hv.x * w0.w + hv.y * w1.w + hv.z * w2.w + hv.w * w3.w;
            }
            *(float4*)&inner[tid * 4] = make_float4(a0, a1, a2, a3);
            __syncthreads();
            const float* xzr = xp + ((size_t)b * T + tt) * G3;
            for (int u = tid; u < H; u += 384) {
                float z  = fsig(xzr[u]     + inner[u]     + zc[u]);
                float r  = fsig(xzr[H + u] + inner[H + u] + rc[u]);
                float hh = tanhf(xzr[2 * H + u] + bh0[u] + r * (inner[2 * H + u] + bh1[u]));
                float hn = z * h[u] + (1.0f - z) * hh;
                h[u] = hn;
                ys[((size_t)b * T + tt) * H + u] = hn;
            }
            __syncthreads();
        } else {
            // masked: h carries through; output (= ys*mask in reference) is 0
            for (int u = tid; u < H; u += 384)
                ys[((size_t)b * T + tt) * H + u] = 0.0f;
        }
    }
    __syncthreads();
    for (int u = tid; u < H; u += 384)
        hfin[((size_t)dir * B + b) * H + u] = h[u];
}

// ---------------------------------------------------------------------------
// Final assembly: out[b][t][0:512]=YF4, [512:1024]=YB4 ; then hidden concat
// ---------------------------------------------------------------------------
__global__ __launch_bounds__(256)
void final_assemble(const float* __restrict__ YF, const float* __restrict__ YB,
                    const float* __restrict__ hf, float* __restrict__ out) {
    int i = blockIdx.x * 256 + threadIdx.x;
    int e = i * 4;
    const int OUT = B * 128 * 1024;
    if (e < OUT) {
        int b = e >> 17, t = (e >> 10) & 127, g = e & 1023;
        const float* src = (g < 512)
            ? &YF[((size_t)b * 128 + t) * 512 + g]
            : &YB[((size_t)b * 128 + t) * 512 + (g - 512)];
        *(float4*)(out + e) = *(const float4*)src;
    } else {
        int e2 = e - OUT;
        int b = e2 >> 10, g = e2 & 1023;
        const float* src = (g < 512) ? &hf[(size_t)b * 512 + g]
                                     : &hf[(size_t)(B + b) * 512 + (g - 512)];
        *(float4*)(out + e) = *(const float4*)src;
    }
}

// ---------------------------------------------------------------------------
extern "C" void kernel_launch(void* const* d_in, const int* in_sizes, int n_in,
                              void* d_out, int out_size, void* d_ws, size_t ws_size,
                              hipStream_t stream) {
    (void)d_ws; (void)ws_size;
    const float* inputs = (const float*)d_in[0];
    const float *k_[4][2], *r_[4][2], *bb_[4][2];
    int idx = 3;
    for (int l = 0; l < 4; ++l)
        for (int d = 0; d < 2; ++d) {
            k_[l][d]  = (const float*)d_in[idx++];
            r_[l][d]  = (const float*)d_in[idx++];
            bb_[l][d] = (const float*)d_in[idx++];
        }

    // resolve device-global scratch addresses (host-side symbol lookup is
    // illegal here; use a tiny kernel-free trick: hipGetSymbolAddress is not
    // graph-capture-hostile, it is a driver query, but to stay safe we take
    // addresses inside kernels via __device__ pointers baked at compile time)
    float* XPF  = nullptr; float* XPB = nullptr;
    float* YF   = nullptr; float* YB  = nullptr;
    float* HFIN = nullptr;
    int *MK1 = nullptr, *MK2 = nullptr, *MK3 = nullptr, *MK4 = nullptr;
    hipGetSymbolAddress((void**)&XPF,  HIP_SYMBOL(g_XPF));
    hipGetSymbolAddress((void**)&XPB,  HIP_SYMBOL(g_XPB));
    hipGetSymbolAddress((void**)&YF,   HIP_SYMBOL(g_YF));
    hipGetSymbolAddress((void**)&YB,   HIP_SYMBOL(g_YB));
    hipGetSymbolAddress((void**)&HFIN, HIP_SYMBOL(g_HFIN));
    hipGetSymbolAddress((void**)&MK1,  HIP_SYMBOL(g_MK1));
    hipGetSymbolAddress((void**)&MK2,  HIP_SYMBOL(g_MK2));
    hipGetSymbolAddress((void**)&MK3,  HIP_SYMBOL(g_MK3));
    hipGetSymbolAddress((void**)&MK4,  HIP_SYMBOL(g_MK4));

    // masks
    mask1_kernel<<<B * T1 / 4, 256, 0, stream>>>(inputs, MK1);
    mask_down<<<(B * (T1 / 2) + 255) / 256, 256, 0, stream>>>(MK1, MK2, B * (T1 / 2), T1 / 2);
    mask_down<<<(B * (T1 / 4) + 255) / 256, 256, 0, stream>>>(MK2, MK3, B * (T1 / 4), T1 / 4);
    mask_down<<<(B * (T1 / 8) + 255) / 256, 256, 0, stream>>>(MK3, MK4, B * (T1 / 8), T1 / 8);

    // ---- layer 1 (input features, K=240) ----
    gemm_xproj<0><<<dim3(12, B * T1 / 128), 256, 0, stream>>>(
        inputs, nullptr, nullptr, k_[0][0], XPF, B * T1, F0, 1);
    gemm_xproj<0><<<dim3(12, B * T1 / 128), 256, 0, stream>>>(
        inputs, nullptr, nullptr, k_[0][1], XPB, B * T1, F0, 1);
    gru_rec<<<64, 384, 0, stream>>>(XPF, XPB, r_[0][0], r_[0][1], bb_[0][0], bb_[0][1],
                                    YF, YB, HFIN, MK1, T1);

    // ---- layers 2..4 (pyramid input, K=2048) ----
    int T = T1 / 2;
    for (int l = 1; l < 4; ++l) {
        int M = B * T;
        const int* mk = (l == 1) ? MK2 : (l == 2) ? MK3 : MK4;
        gemm_xproj<1><<<dim3(12, M / 128), 256, 0, stream>>>(
            nullptr, YF, YB, k_[l][0], XPF, M, 2048, T);
        gemm_xproj<1><<<dim3(12, M / 128), 256, 0, stream>>>(
            nullptr, YF, YB, k_[l][1], XPB, M, 2048, T);
        gru_rec<<<64, 384, 0, stream>>>(XPF, XPB, r_[l][0], r_[l][1], bb_[l][0], bb_[l][1],
                                        YF, YB, HFIN, mk, T);
        T >>= 1;
    }

    // ---- output ----
    final_assemble<<<(out_size / 4 + 255) / 256, 256, 0, stream>>>(YF, YB, HFIN, (float*)d_out);
}